// Round 18
// baseline (5807.796 us; speedup 1.0000x reference)
//
#include <hip/hip_runtime.h>
#include <math.h>

#define DIM 32
#define BLK 256
#define JSPLIT 16   // j-chunks -> grid.y ; 64 fp64-atomic writers per out row
#define RI   4      // i-tiles per wave (64 rows) — R14/R16 sweet spot
#define ITPB (4*RI) // i-tiles per block (16 tiles = 256 rows)
#define GTT  32     // j-tiles between fp32->fp64 flushes (512 j)

typedef _Float16 half8 __attribute__((ext_vector_type(8)));
typedef float    f32x4 __attribute__((ext_vector_type(4)));

struct hl16 { half8 h; half8 l; };   // 32 B fragment record (hi + lo plane)

// out[i] = 2^(c2*||x_i||^2) * sum_j pf_j * 2^(<mf*x_i, y_j> - 64)
//   where pf_j = 2^(c2*||y_j||^2 + 64)  (fp64-computed in prep, fp32 stored)
//   c2 = -ls*log2(e) (fp64, exact per-i factor in fp64 finish kernel)
//   f16 hi/lo split (lo plane *2^12 to stay f16-normal):
//     cm = Ah*Bh + (-64 quad) ; cl = Ah*Bl + Al*Bh ; f = fma(cl,2^-12,cm)
//     accf += exp2(f) * pf   (v_fmac; -64 bias keeps 2^f in fp32 range)
//   fp32 partials -> fp64 atomics EVERY GTT-GROUP (no accd register array).
// R17 = R16 minus accd: R16's fp64 accd[4][4] lived in AGPRs (unified file)
//   -> ~168 regs/wave -> only 12 waves/CU despite VGPR_Count=64; issue port
//   idle 26%. Flushing each group straight to fp64 atomics (4x per kernel)
//   frees the AGPRs -> target 5-6 blocks/CU, issue port filled by TLP.

__global__ __launch_bounds__(BLK) void rbf_prep(
    const float* __restrict__ lsp, const float* __restrict__ x,
    const float* __restrict__ y, int n, int m, int xblocks,
    double* __restrict__ acc, double* __restrict__ scale,
    float* __restrict__ pf, hl16* __restrict__ xhl, hl16* __restrict__ yhl)
{
    const double c2 = -(double)lsp[0] * 1.4426950408889634074; // -ls*log2(e)
    if ((int)blockIdx.x < xblocks) {
        const int i = blockIdx.x * BLK + threadIdx.x;
        if (i >= n) return;
        const float mf = (float)(-2.0 * c2);
        const float* xp = x + (size_t)i * DIM;
        double xs = 0.0;
        #pragma unroll
        for (int d = 0; d < DIM; ++d) { double v = (double)xp[d]; xs = fma(v, v, xs); }
        acc[i] = 0.0;
        scale[i] = exp2(c2 * xs);
        const int it = i >> 4, r15 = i & 15;
        #pragma unroll
        for (int q = 0; q < 4; ++q) {
            half8 hh, hl;
            #pragma unroll
            for (int d = 0; d < 8; ++d) {
                float v = xp[q * 8 + d] * mf;
                _Float16 h = (_Float16)v;
                hh[d] = h;
                hl[d] = (_Float16)((v - (float)h) * 4096.0f);
            }
            xhl[it * 64 + q * 16 + r15].h = hh;
            xhl[it * 64 + q * 16 + r15].l = hl;
        }
    } else {
        const int i = (blockIdx.x - xblocks) * BLK + threadIdx.x;
        if (i >= m) return;
        const float* yp = y + (size_t)i * DIM;
        double ys = 0.0;
        #pragma unroll
        for (int d = 0; d < DIM; ++d) { double v = (double)yp[d]; ys = fma(v, v, ys); }
        pf[i] = (float)exp2(c2 * ys + 64.0);   // 2^(bf+64), fp64-accurate
        const int it = i >> 4, r15 = i & 15;
        #pragma unroll
        for (int q = 0; q < 4; ++q) {
            half8 hh, hl;
            #pragma unroll
            for (int d = 0; d < 8; ++d) {
                float v = yp[q * 8 + d];
                _Float16 h = (_Float16)v;
                hh[d] = h;
                hl[d] = (_Float16)((v - (float)h) * 4096.0f);
            }
            yhl[it * 64 + q * 16 + r15].h = hh;
            yhl[it * 64 + q * 16 + r15].l = hl;
        }
    }
}

__global__ __launch_bounds__(BLK, 2) void rbf_main(
    const hl16* __restrict__ xhl, const hl16* __restrict__ yhl,
    const float* __restrict__ pfq, double* __restrict__ acc, int chunk_j)
{
    const int lane = threadIdx.x & 63;
    const int wave = threadIdx.x >> 6;
    const int itbase = blockIdx.x * ITPB + wave * RI;
    const int c15 = lane & 15;

    half8 ah[RI], al[RI];
    #pragma unroll
    for (int r = 0; r < RI; ++r) {
        ah[r] = xhl[(itbase + r) * 64 + lane].h;
        al[r] = xhl[(itbase + r) * 64 + lane].l;
    }

    const int jt0 = (blockIdx.y * chunk_j) >> 4;
    const int njt = chunk_j >> 4;                 // 128 j-tiles per chunk

    const f32x4 zq = {0.0f, 0.0f, 0.0f, 0.0f};            // persistent zero C
    const f32x4 nq = {-64.0f, -64.0f, -64.0f, -64.0f};    // persistent bias C
    const float k12 = 0x1p-12f;

    // uniform-pointer-bump addressing: fixed per-lane vaddr; bases bumped
    // one tile per step on the scalar pipe; load offsets imm {0,16,2048,2064}
    const hl16*  __restrict__ yp = yhl + (size_t)jt0 * 64;   // uniform base
    const float* __restrict__ bp = pfq + jt0 * 16;           // uniform base

    // 2-slot parity double-buffered B fragments
    half8 bh[2], bl[2];
    float pfv[2];
    bh[0] = yp[lane].h;
    bl[0] = yp[lane].l;
    pfv[0] = bp[c15];

    for (int g = 0; g < njt / GTT; ++g) {
        float accf[RI][4];
        #pragma unroll
        for (int r = 0; r < RI; ++r)
            #pragma unroll
            for (int e = 0; e < 4; ++e) accf[r][e] = 0.0f;

        #pragma unroll
        for (int tt = 0; tt < GTT; ++tt) {
            const int cur = tt & 1, nxt = cur ^ 1;
            // prefetch next tile (last prefetch of the last group reads one
            // tile past the chunk — never consumed; ws layout keeps it in ws)
            bh[nxt] = yp[64 + lane].h;
            bl[nxt] = yp[64 + lane].l;
            pfv[nxt] = bp[16 + c15];

            #pragma unroll
            for (int r = 0; r < RI; ++r) {
                f32x4 cm = __builtin_amdgcn_mfma_f32_16x16x32_f16(ah[r], bh[cur], nq, 0, 0, 0);
                f32x4 cl = __builtin_amdgcn_mfma_f32_16x16x32_f16(al[r], bh[cur], zq, 0, 0, 0);
                cl = __builtin_amdgcn_mfma_f32_16x16x32_f16(ah[r], bl[cur], cl, 0, 0, 0);
                #pragma unroll
                for (int e = 0; e < 4; ++e) {
                    float f = __builtin_fmaf(cl[e], k12, cm[e]);
                    float e2 = __builtin_amdgcn_exp2f(f);
                    accf[r][e] = __builtin_fmaf(e2, pfv[cur], accf[r][e]); // v_fmac
                }
            }
            yp += 64;   // one tile = 2048 B; uniform s_add on scalar pipe
            bp += 16;   // 64 B
        }

        // group flush: cvt -> fp64 butterfly over the 16-lane col groups ->
        // atomicAdd. 4x per kernel; frees accd's AGPRs (the R16 residency cap).
        #pragma unroll
        for (int r = 0; r < RI; ++r) {
            #pragma unroll
            for (int e = 0; e < 4; ++e) {
                double v = (double)accf[r][e];
                v += __shfl_xor(v, 1, 64);
                v += __shfl_xor(v, 2, 64);
                v += __shfl_xor(v, 4, 64);
                v += __shfl_xor(v, 8, 64);
                if (c15 == 0) {
                    int row = (itbase + r) * 16 + (lane >> 4) * 4 + e;
                    atomicAdd(&acc[row], v);   // fp64, JSPLIT*4 writers per row
                }
            }
        }
    }
}

__global__ __launch_bounds__(BLK) void rbf_finish(
    const double* __restrict__ acc, const double* __restrict__ scale,
    float* __restrict__ out, int n)
{
    int i = blockIdx.x * BLK + threadIdx.x;
    if (i < n) out[i] = (float)(acc[i] * scale[i]);
}

extern "C" void kernel_launch(void* const* d_in, const int* in_sizes, int n_in,
                              void* d_out, int out_size, void* d_ws, size_t ws_size,
                              hipStream_t stream)
{
    const float* ls = (const float*)d_in[0];
    const float* x  = (const float*)d_in[1];
    const float* y  = (const float*)d_in[2];
    const int n = in_sizes[1] / DIM;   // 32768
    const int m = in_sizes[2] / DIM;   // 32768
    float* out = (float*)d_out;

    // ws layout (ORDER MATTERS — one-past-end prefetches must stay in ws):
    //   acc[n] f64 | scale[n] f64 | pf[m] f32 | yhl | xhl   (~8.6 MB)
    char* ws = (char*)d_ws;
    double* acc   = (double*)ws;
    double* scale = acc + n;
    float*  pf    = (float*)(scale + n);
    hl16*   yhl   = (hl16*)(pf + m);
    hl16*   xhl   = yhl + (size_t)(m / 16) * 64;

    const int xblocks = (n + BLK - 1) / BLK;      // 128
    const int yblocks = (m + BLK - 1) / BLK;      // 128
    rbf_prep<<<xblocks + yblocks, BLK, 0, stream>>>(
        ls, x, y, n, m, xblocks, acc, scale, pf, xhl, yhl);

    const int chunk = m / JSPLIT;                 // 2048
    dim3 grid(n / (16 * ITPB), JSPLIT);           // 128 x 16
    rbf_main<<<grid, BLK, 0, stream>>>(xhl, yhl, pf, acc, chunk);

    rbf_finish<<<(n + BLK - 1) / BLK, BLK, 0, stream>>>(acc, scale, out, n);
}

// Round 19
// 272.262 us; speedup vs baseline: 21.3317x; 21.3317x over previous
//
#include <hip/hip_runtime.h>
#include <math.h>

#define DIM 32
#define BLK 256
#define JSPLIT 16   // j-chunks -> grid.y ; 16 fp64-atomic writers per out row
#define RI   4      // i-tiles per wave (64 rows) — R14/R16 sweet spot
#define ITPB (4*RI) // i-tiles per block (16 tiles = 256 rows)
#define GTT  32     // j-tiles between fp32->fp64 flushes (512 j)

typedef _Float16 half8 __attribute__((ext_vector_type(8)));
typedef float    f32x4 __attribute__((ext_vector_type(4)));

struct hl16 { half8 h; half8 l; };   // 32 B fragment record (hi + lo plane)

// out[i] = 2^(c2*||x_i||^2) * sum_j pf_j * 2^(<mf*x_i, y_j> - 64)
//   where pf_j = 2^(c2*||y_j||^2 + 64)  (fp64-computed in prep, fp32 stored)
//   c2 = -ls*log2(e) (fp64, exact per-i factor in fp64 finish kernel)
//   f16 hi/lo split (lo plane *2^12 to stay f16-normal):
//     cm = Ah*Bh + (-64 quad) ; cl = Ah*Bl + Al*Bh ; f = fma(cl,2^-12,cm)
//     accf += exp2(f) * pf   (v_fmac; -64 bias keeps 2^f in fp32 range)
//   fp32 partials -> fp64 accumulator in LDS every GTT tiles (thread-private
//   slots, no barriers); one post-loop fp64 butterfly + atomicAdd per row.
// R18 = R16 with accd moved to LDS. R16's fp64 accd[4][4] parked in AGPRs
//   (unified alloc ~170/wave -> 12 waves/CU, issue port 26% idle). R17's
//   in-loop shfl flush spilled to scratch (20 GB HBM — never again).
//   LDS accs[16][256] = 32 KB/block: 5 blocks/CU fit 160 KB exactly;
//   arithmetic order bit-identical to R16.

__global__ __launch_bounds__(BLK) void rbf_prep(
    const float* __restrict__ lsp, const float* __restrict__ x,
    const float* __restrict__ y, int n, int m, int xblocks,
    double* __restrict__ acc, double* __restrict__ scale,
    float* __restrict__ pf, hl16* __restrict__ xhl, hl16* __restrict__ yhl)
{
    const double c2 = -(double)lsp[0] * 1.4426950408889634074; // -ls*log2(e)
    if ((int)blockIdx.x < xblocks) {
        const int i = blockIdx.x * BLK + threadIdx.x;
        if (i >= n) return;
        const float mf = (float)(-2.0 * c2);
        const float* xp = x + (size_t)i * DIM;
        double xs = 0.0;
        #pragma unroll
        for (int d = 0; d < DIM; ++d) { double v = (double)xp[d]; xs = fma(v, v, xs); }
        acc[i] = 0.0;
        scale[i] = exp2(c2 * xs);
        const int it = i >> 4, r15 = i & 15;
        #pragma unroll
        for (int q = 0; q < 4; ++q) {
            half8 hh, hl;
            #pragma unroll
            for (int d = 0; d < 8; ++d) {
                float v = xp[q * 8 + d] * mf;
                _Float16 h = (_Float16)v;
                hh[d] = h;
                hl[d] = (_Float16)((v - (float)h) * 4096.0f);
            }
            xhl[it * 64 + q * 16 + r15].h = hh;
            xhl[it * 64 + q * 16 + r15].l = hl;
        }
    } else {
        const int i = (blockIdx.x - xblocks) * BLK + threadIdx.x;
        if (i >= m) return;
        const float* yp = y + (size_t)i * DIM;
        double ys = 0.0;
        #pragma unroll
        for (int d = 0; d < DIM; ++d) { double v = (double)yp[d]; ys = fma(v, v, ys); }
        pf[i] = (float)exp2(c2 * ys + 64.0);   // 2^(bf+64), fp64-accurate
        const int it = i >> 4, r15 = i & 15;
        #pragma unroll
        for (int q = 0; q < 4; ++q) {
            half8 hh, hl;
            #pragma unroll
            for (int d = 0; d < 8; ++d) {
                float v = yp[q * 8 + d];
                _Float16 h = (_Float16)v;
                hh[d] = h;
                hl[d] = (_Float16)((v - (float)h) * 4096.0f);
            }
            yhl[it * 64 + q * 16 + r15].h = hh;
            yhl[it * 64 + q * 16 + r15].l = hl;
        }
    }
}

__global__ __launch_bounds__(BLK, 2) void rbf_main(
    const hl16* __restrict__ xhl, const hl16* __restrict__ yhl,
    const float* __restrict__ pfq, double* __restrict__ acc, int chunk_j)
{
    __shared__ double accs[RI * 4][BLK];   // 32 KB; thread-private columns

    const int tid = threadIdx.x;
    const int lane = threadIdx.x & 63;
    const int wave = threadIdx.x >> 6;
    const int itbase = blockIdx.x * ITPB + wave * RI;
    const int c15 = lane & 15;

    #pragma unroll
    for (int s = 0; s < RI * 4; ++s) accs[s][tid] = 0.0;   // private: no barrier

    half8 ah[RI], al[RI];
    #pragma unroll
    for (int r = 0; r < RI; ++r) {
        ah[r] = xhl[(itbase + r) * 64 + lane].h;
        al[r] = xhl[(itbase + r) * 64 + lane].l;
    }

    const int jt0 = (blockIdx.y * chunk_j) >> 4;
    const int njt = chunk_j >> 4;                 // 128 j-tiles per chunk

    const f32x4 zq = {0.0f, 0.0f, 0.0f, 0.0f};            // persistent zero C
    const f32x4 nq = {-64.0f, -64.0f, -64.0f, -64.0f};    // persistent bias C
    const float k12 = 0x1p-12f;

    // uniform-pointer-bump addressing: fixed per-lane vaddr; bases bumped
    // one tile per step on the scalar pipe; load offsets imm {0,16,2048,2064}
    const hl16*  __restrict__ yp = yhl + (size_t)jt0 * 64;   // uniform base
    const float* __restrict__ bp = pfq + jt0 * 16;           // uniform base

    // 2-slot parity double-buffered B fragments
    half8 bh[2], bl[2];
    float pfv[2];
    bh[0] = yp[lane].h;
    bl[0] = yp[lane].l;
    pfv[0] = bp[c15];

    for (int g = 0; g < njt / GTT; ++g) {
        float accf[RI][4];
        #pragma unroll
        for (int r = 0; r < RI; ++r)
            #pragma unroll
            for (int e = 0; e < 4; ++e) accf[r][e] = 0.0f;

        #pragma unroll
        for (int tt = 0; tt < GTT; ++tt) {
            const int cur = tt & 1, nxt = cur ^ 1;
            // prefetch next tile (last prefetch of the last group reads one
            // tile past the chunk — never consumed; ws layout keeps it in ws)
            bh[nxt] = yp[64 + lane].h;
            bl[nxt] = yp[64 + lane].l;
            pfv[nxt] = bp[16 + c15];

            #pragma unroll
            for (int r = 0; r < RI; ++r) {
                f32x4 cm = __builtin_amdgcn_mfma_f32_16x16x32_f16(ah[r], bh[cur], nq, 0, 0, 0);
                f32x4 cl = __builtin_amdgcn_mfma_f32_16x16x32_f16(al[r], bh[cur], zq, 0, 0, 0);
                cl = __builtin_amdgcn_mfma_f32_16x16x32_f16(ah[r], bl[cur], cl, 0, 0, 0);
                #pragma unroll
                for (int e = 0; e < 4; ++e) {
                    float f = __builtin_fmaf(cl[e], k12, cm[e]);
                    float e2 = __builtin_amdgcn_exp2f(f);
                    accf[r][e] = __builtin_fmaf(e2, pfv[cur], accf[r][e]); // v_fmac
                }
            }
            yp += 64;   // one tile = 2048 B; uniform s_add on scalar pipe
            bp += 16;   // 64 B
        }

        // group flush into thread-private LDS fp64 slots (no shfl, no barrier)
        #pragma unroll
        for (int r = 0; r < RI; ++r)
            #pragma unroll
            for (int e = 0; e < 4; ++e)
                accs[r * 4 + e][tid] += (double)accf[r][e];
    }

    // post-loop: fp64 butterfly over the 16-lane col groups -> atomics
    #pragma unroll
    for (int r = 0; r < RI; ++r) {
        #pragma unroll
        for (int e = 0; e < 4; ++e) {
            double v = accs[r * 4 + e][tid];
            v += __shfl_xor(v, 1, 64);
            v += __shfl_xor(v, 2, 64);
            v += __shfl_xor(v, 4, 64);
            v += __shfl_xor(v, 8, 64);
            if (c15 == 0) {
                int row = (itbase + r) * 16 + (lane >> 4) * 4 + e;
                atomicAdd(&acc[row], v);   // fp64, JSPLIT writers per row
            }
        }
    }
}

__global__ __launch_bounds__(BLK) void rbf_finish(
    const double* __restrict__ acc, const double* __restrict__ scale,
    float* __restrict__ out, int n)
{
    int i = blockIdx.x * BLK + threadIdx.x;
    if (i < n) out[i] = (float)(acc[i] * scale[i]);
}

extern "C" void kernel_launch(void* const* d_in, const int* in_sizes, int n_in,
                              void* d_out, int out_size, void* d_ws, size_t ws_size,
                              hipStream_t stream)
{
    const float* ls = (const float*)d_in[0];
    const float* x  = (const float*)d_in[1];
    const float* y  = (const float*)d_in[2];
    const int n = in_sizes[1] / DIM;   // 32768
    const int m = in_sizes[2] / DIM;   // 32768
    float* out = (float*)d_out;

    // ws layout (ORDER MATTERS — one-past-end prefetches must stay in ws):
    //   acc[n] f64 | scale[n] f64 | pf[m] f32 | yhl | xhl   (~8.6 MB)
    char* ws = (char*)d_ws;
    double* acc   = (double*)ws;
    double* scale = acc + n;
    float*  pf    = (float*)(scale + n);
    hl16*   yhl   = (hl16*)(pf + m);
    hl16*   xhl   = yhl + (size_t)(m / 16) * 64;

    const int xblocks = (n + BLK - 1) / BLK;      // 128
    const int yblocks = (m + BLK - 1) / BLK;      // 128
    rbf_prep<<<xblocks + yblocks, BLK, 0, stream>>>(
        ls, x, y, n, m, xblocks, acc, scale, pf, xhl, yhl);

    const int chunk = m / JSPLIT;                 // 2048
    dim3 grid(n / (16 * ITPB), JSPLIT);           // 128 x 16
    rbf_main<<<grid, BLK, 0, stream>>>(xhl, yhl, pf, acc, chunk);

    rbf_finish<<<(n + BLK - 1) / BLK, BLK, 0, stream>>>(acc, scale, out, n);
}

// Round 20
// 271.116 us; speedup vs baseline: 21.4218x; 1.0042x over previous
//
#include <hip/hip_runtime.h>
#include <math.h>

#define DIM 32
#define BLK 256
#define JSPLIT 16   // j-chunks -> grid.y ; 16 fp64-atomic writers per out row
#define RI   4      // i-tiles per wave (64 rows) — R14/R16 sweet spot: 64 VGPR
#define ITPB (4*RI) // i-tiles per block (16 tiles = 256 rows)
#define GTT  32     // j-tiles between fp32->fp64 flushes (512 j)

typedef _Float16 half8 __attribute__((ext_vector_type(8)));
typedef float    f32x4 __attribute__((ext_vector_type(4)));

struct hl16 { half8 h; half8 l; };   // 32 B fragment record (hi + lo plane)

// FINAL (R19 = exact R16, best of 19 rounds: main 219 us, total 270 us).
// out[i] = 2^(c2*||x_i||^2) * sum_j pf_j * 2^(<mf*x_i, y_j> - 64)
//   pf_j = 2^(c2*||y_j||^2 + 64)  (fp64-computed in prep, fp32 stored)
//   c2 = -ls*log2(e) (fp64, exact per-i factor in fp64 finish kernel)
//   f16 hi/lo split (lo plane *2^12 to stay f16-normal):
//     cm = Ah*Bh + (-64 quad) ; cl = Ah*Bl + Al*Bh ; f = fma(cl,2^-12,cm)
//     accf += exp2(f) * pf   (v_fmac; -64 bias keeps 2^f in fp32 range)
//   fp32 partials -> fp64 accd every GTT tiles; fp64 butterfly + atomics.
// Session ledger (what's proven on MI355X for this kernel):
//   GOOD: f16 hi/lo 3-MFMA split (334->261), RI=4 @ (256,2) (237->220),
//     scalar epilogue, 2-slot parity prefetch, pointer-bump addressing,
//     split x/y prep (58->39 us overhead), fp64-factored exponent numerics
//     (absmax 7.5e-9 vs 2.4e-5 threshold).
//   BAD: runtime-indexed pipeline slots (R6), poly exp2 (R7), packed f32x2
//     epilogue (R10/R11), 4-slot B state (R10), fused finish w/ threadfence
//     (R12), RI=8 (R15), in-loop shfl flush (R17 scratch-spill disaster),
//     LDS accumulator (R18 neutral-worse).
//   Structural floor: 2^30 v_exp_f32 = ~66% of issued cycles; six different
//   instruction streams all land 219-237 us main. This is the ceiling.

__global__ __launch_bounds__(BLK) void rbf_prep(
    const float* __restrict__ lsp, const float* __restrict__ x,
    const float* __restrict__ y, int n, int m, int xblocks,
    double* __restrict__ acc, double* __restrict__ scale,
    float* __restrict__ pf, hl16* __restrict__ xhl, hl16* __restrict__ yhl)
{
    const double c2 = -(double)lsp[0] * 1.4426950408889634074; // -ls*log2(e)
    if ((int)blockIdx.x < xblocks) {
        const int i = blockIdx.x * BLK + threadIdx.x;
        if (i >= n) return;
        const float mf = (float)(-2.0 * c2);
        const float* xp = x + (size_t)i * DIM;
        double xs = 0.0;
        #pragma unroll
        for (int d = 0; d < DIM; ++d) { double v = (double)xp[d]; xs = fma(v, v, xs); }
        acc[i] = 0.0;
        scale[i] = exp2(c2 * xs);
        const int it = i >> 4, r15 = i & 15;
        #pragma unroll
        for (int q = 0; q < 4; ++q) {
            half8 hh, hl;
            #pragma unroll
            for (int d = 0; d < 8; ++d) {
                float v = xp[q * 8 + d] * mf;
                _Float16 h = (_Float16)v;
                hh[d] = h;
                hl[d] = (_Float16)((v - (float)h) * 4096.0f);
            }
            xhl[it * 64 + q * 16 + r15].h = hh;
            xhl[it * 64 + q * 16 + r15].l = hl;
        }
    } else {
        const int i = (blockIdx.x - xblocks) * BLK + threadIdx.x;
        if (i >= m) return;
        const float* yp = y + (size_t)i * DIM;
        double ys = 0.0;
        #pragma unroll
        for (int d = 0; d < DIM; ++d) { double v = (double)yp[d]; ys = fma(v, v, ys); }
        pf[i] = (float)exp2(c2 * ys + 64.0);   // 2^(bf+64), fp64-accurate
        const int it = i >> 4, r15 = i & 15;
        #pragma unroll
        for (int q = 0; q < 4; ++q) {
            half8 hh, hl;
            #pragma unroll
            for (int d = 0; d < 8; ++d) {
                float v = yp[q * 8 + d];
                _Float16 h = (_Float16)v;
                hh[d] = h;
                hl[d] = (_Float16)((v - (float)h) * 4096.0f);
            }
            yhl[it * 64 + q * 16 + r15].h = hh;
            yhl[it * 64 + q * 16 + r15].l = hl;
        }
    }
}

__global__ __launch_bounds__(BLK, 2) void rbf_main(
    const hl16* __restrict__ xhl, const hl16* __restrict__ yhl,
    const float* __restrict__ pfq, double* __restrict__ acc, int chunk_j)
{
    const int lane = threadIdx.x & 63;
    const int wave = threadIdx.x >> 6;
    const int itbase = blockIdx.x * ITPB + wave * RI;
    const int c15 = lane & 15;

    half8 ah[RI], al[RI];
    #pragma unroll
    for (int r = 0; r < RI; ++r) {
        ah[r] = xhl[(itbase + r) * 64 + lane].h;
        al[r] = xhl[(itbase + r) * 64 + lane].l;
    }

    const int jt0 = (blockIdx.y * chunk_j) >> 4;
    const int njt = chunk_j >> 4;                 // 128 j-tiles per chunk

    const f32x4 zq = {0.0f, 0.0f, 0.0f, 0.0f};            // persistent zero C
    const f32x4 nq = {-64.0f, -64.0f, -64.0f, -64.0f};    // persistent bias C
    const float k12 = 0x1p-12f;

    double accd[RI][4];
    #pragma unroll
    for (int r = 0; r < RI; ++r)
        #pragma unroll
        for (int e = 0; e < 4; ++e) accd[r][e] = 0.0;

    // uniform-pointer-bump addressing: fixed per-lane vaddr; bases bumped
    // one tile per step on the scalar pipe; load offsets imm {0,16,2048,2064}
    const hl16*  __restrict__ yp = yhl + (size_t)jt0 * 64;   // uniform base
    const float* __restrict__ bp = pfq + jt0 * 16;           // uniform base

    // 2-slot parity double-buffered B fragments
    half8 bh[2], bl[2];
    float pfv[2];
    bh[0] = yp[lane].h;
    bl[0] = yp[lane].l;
    pfv[0] = bp[c15];

    for (int g = 0; g < njt / GTT; ++g) {
        float accf[RI][4];
        #pragma unroll
        for (int r = 0; r < RI; ++r)
            #pragma unroll
            for (int e = 0; e < 4; ++e) accf[r][e] = 0.0f;

        #pragma unroll
        for (int tt = 0; tt < GTT; ++tt) {
            const int cur = tt & 1, nxt = cur ^ 1;
            // prefetch next tile (last prefetch of the last group reads one
            // tile past the chunk — never consumed; ws layout keeps it in ws)
            bh[nxt] = yp[64 + lane].h;
            bl[nxt] = yp[64 + lane].l;
            pfv[nxt] = bp[16 + c15];

            #pragma unroll
            for (int r = 0; r < RI; ++r) {
                f32x4 cm = __builtin_amdgcn_mfma_f32_16x16x32_f16(ah[r], bh[cur], nq, 0, 0, 0);
                f32x4 cl = __builtin_amdgcn_mfma_f32_16x16x32_f16(al[r], bh[cur], zq, 0, 0, 0);
                cl = __builtin_amdgcn_mfma_f32_16x16x32_f16(ah[r], bl[cur], cl, 0, 0, 0);
                #pragma unroll
                for (int e = 0; e < 4; ++e) {
                    float f = __builtin_fmaf(cl[e], k12, cm[e]);
                    float e2 = __builtin_amdgcn_exp2f(f);
                    accf[r][e] = __builtin_fmaf(e2, pfv[cur], accf[r][e]); // v_fmac
                }
            }
            yp += 64;   // one tile = 2048 B; uniform s_add on scalar pipe
            bp += 16;   // 64 B
        }
        #pragma unroll
        for (int r = 0; r < RI; ++r)
            #pragma unroll
            for (int e = 0; e < 4; ++e) accd[r][e] += (double)accf[r][e];
    }

    // sum the 16 j-columns: fp64 butterfly across the 16-lane col groups
    #pragma unroll
    for (int r = 0; r < RI; ++r) {
        #pragma unroll
        for (int e = 0; e < 4; ++e) {
            double v = accd[r][e];
            v += __shfl_xor(v, 1, 64);
            v += __shfl_xor(v, 2, 64);
            v += __shfl_xor(v, 4, 64);
            v += __shfl_xor(v, 8, 64);
            if (c15 == 0) {
                int row = (itbase + r) * 16 + (lane >> 4) * 4 + e;
                atomicAdd(&acc[row], v);   // fp64, JSPLIT writers per row
            }
        }
    }
}

__global__ __launch_bounds__(BLK) void rbf_finish(
    const double* __restrict__ acc, const double* __restrict__ scale,
    float* __restrict__ out, int n)
{
    int i = blockIdx.x * BLK + threadIdx.x;
    if (i < n) out[i] = (float)(acc[i] * scale[i]);
}

extern "C" void kernel_launch(void* const* d_in, const int* in_sizes, int n_in,
                              void* d_out, int out_size, void* d_ws, size_t ws_size,
                              hipStream_t stream)
{
    const float* ls = (const float*)d_in[0];
    const float* x  = (const float*)d_in[1];
    const float* y  = (const float*)d_in[2];
    const int n = in_sizes[1] / DIM;   // 32768
    const int m = in_sizes[2] / DIM;   // 32768
    float* out = (float*)d_out;

    // ws layout (ORDER MATTERS — one-past-end prefetches must stay in ws):
    //   acc[n] f64 | scale[n] f64 | pf[m] f32 | yhl | xhl   (~8.6 MB)
    char* ws = (char*)d_ws;
    double* acc   = (double*)ws;
    double* scale = acc + n;
    float*  pf    = (float*)(scale + n);
    hl16*   yhl   = (hl16*)(pf + m);
    hl16*   xhl   = yhl + (size_t)(m / 16) * 64;

    const int xblocks = (n + BLK - 1) / BLK;      // 128
    const int yblocks = (m + BLK - 1) / BLK;      // 128
    rbf_prep<<<xblocks + yblocks, BLK, 0, stream>>>(
        ls, x, y, n, m, xblocks, acc, scale, pf, xhl, yhl);

    const int chunk = m / JSPLIT;                 // 2048
    dim3 grid(n / (16 * ITPB), JSPLIT);           // 128 x 16
    rbf_main<<<grid, BLK, 0, stream>>>(xhl, yhl, pf, acc, chunk);

    rbf_finish<<<(n + BLK - 1) / BLK, BLK, 0, stream>>>(acc, scale, out, n);
}